// Round 2
// baseline (214.706 us; speedup 1.0000x reference)
//
#include <hip/hip_runtime.h>
#include <math.h>

#define WS   10
#define HID  32
#define BDIM 256
#define PTS  4
#define TILE (BDIM * PTS)   // 1024 t-values per block

__global__ __launch_bounds__(BDIM)
void hurst_mlp_kernel(const float* __restrict__ returns,
                      const float* __restrict__ W1, const float* __restrict__ b1,
                      const float* __restrict__ W2, const float* __restrict__ b2,
                      const float* __restrict__ W3, const float* __restrict__ b3,
                      float* __restrict__ out, int T)
{
    // Transposed weights in LDS: row j is contiguous over the reduction index
    // -> wave-uniform ds_read_b128, broadcast (no bank conflicts).
    __shared__ float sW1t[HID][WS];    // sW1t[j][k] = W1[k*HID + j]
    __shared__ float sW2t[HID][HID];   // sW2t[j][i] = W2[i*HID + j]
    __shared__ float sb1[HID];
    __shared__ float sb2[HID];
    __shared__ float sW3[HID];
    __shared__ float sb3s;
    __shared__ float sret[TILE + WS];

    const int tid = threadIdx.x;

    for (int i = tid; i < WS * HID; i += BDIM) {
        int k = i / HID, j = i % HID;
        sW1t[j][k] = W1[i];
    }
    for (int i = tid; i < HID * HID; i += BDIM) {
        int k = i / HID, j = i % HID;
        sW2t[j][k] = W2[i];
    }
    if (tid < HID) { sb1[tid] = b1[tid]; sb2[tid] = b2[tid]; sW3[tid] = W3[tid]; }
    if (tid == 0)  { sb3s = b3[0]; }

    const int    b    = blockIdx.y;
    const int    t0   = blockIdx.x * TILE;
    const int    base = (t0 >= WS) ? (t0 - WS) : 0;
    const size_t row  = (size_t)b * (size_t)T;

    for (int i = tid; i < TILE + WS; i += BDIM) {
        int g = base + i;
        sret[i] = (g < T) ? returns[row + g] : 0.0f;
    }
    __syncthreads();

    // ---- load 4 windows per thread (strided by BDIM: coalesced LDS reads) ----
    float w[PTS][WS];
    #pragma unroll
    for (int p = 0; p < PTS; ++p) {
        int t   = t0 + p * BDIM + tid;
        int s   = (t >= WS) ? (t - WS) : 0;   // head columns reuse window 0
        int off = s - base;
        #pragma unroll
        for (int k = 0; k < WS; ++k) w[p][k] = sret[off + k];
    }

    // ---- layer 1: h1 = relu(window @ W1 + b1)  (fully unrolled: h1 in VGPRs) ----
    float h1[PTS][HID];
    #pragma unroll
    for (int j = 0; j < HID; ++j) {
        float wj[WS];
        #pragma unroll
        for (int k = 0; k < WS; ++k) wj[k] = sW1t[j][k];
        float bj = sb1[j];
        #pragma unroll
        for (int p = 0; p < PTS; ++p) {
            float acc = bj;
            #pragma unroll
            for (int k = 0; k < WS; ++k) acc = fmaf(w[p][k], wj[k], acc);
            h1[p][j] = fmaxf(acc, 0.0f);
        }
    }

    // ---- layer 2 + 3 fused: s += W3[j] * relu(h1 @ W2[:,j] + b2[j]) ----
    // j-loop rolled (code size); i-loop unrolled so h1 indices are constant.
    float sacc[PTS];
    #pragma unroll
    for (int p = 0; p < PTS; ++p) sacc[p] = sb3s;

    for (int j = 0; j < HID; ++j) {
        float wj[HID];
        #pragma unroll
        for (int i = 0; i < HID; ++i) wj[i] = sW2t[j][i];
        float bj  = sb2[j];
        float w3j = sW3[j];
        #pragma unroll
        for (int p = 0; p < PTS; ++p) {
            float acc = bj;
            #pragma unroll
            for (int i = 0; i < HID; ++i) acc = fmaf(h1[p][i], wj[i], acc);
            sacc[p] = fmaf(fmaxf(acc, 0.0f), w3j, sacc[p]);
        }
    }

    // ---- epilogue: 0.5 * sigmoid(s) ----
    #pragma unroll
    for (int p = 0; p < PTS; ++p) {
        int t = t0 + p * BDIM + tid;
        float o = 0.5f / (1.0f + __expf(-sacc[p]));
        out[row + t] = o;
    }
}

extern "C" void kernel_launch(void* const* d_in, const int* in_sizes, int n_in,
                              void* d_out, int out_size, void* d_ws, size_t ws_size,
                              hipStream_t stream) {
    const float* returns = (const float*)d_in[0];
    const float* W1      = (const float*)d_in[1];
    const float* b1      = (const float*)d_in[2];
    const float* W2      = (const float*)d_in[3];
    const float* b2      = (const float*)d_in[4];
    const float* W3      = (const float*)d_in[5];
    const float* b3      = (const float*)d_in[6];
    float* out = (float*)d_out;

    const int T = 4096;
    const int B = out_size / T;   // 1024

    dim3 grid(T / TILE, B, 1);    // (4, 1024)
    dim3 block(BDIM, 1, 1);
    hurst_mlp_kernel<<<grid, block, 0, stream>>>(returns, W1, b1, W2, b2, W3, b3, out, T);
}

// Round 4
// 172.966 us; speedup vs baseline: 1.2413x; 1.2413x over previous
//
#include <hip/hip_runtime.h>
#include <math.h>

typedef _Float16 h2  __attribute__((ext_vector_type(2)));
typedef __fp16   h2a __attribute__((ext_vector_type(2)));   // what cvt_pkrtz returns

#define WS   10
#define HID  32
#define BDIM 256
#define PTS  4
#define TILE (BDIM * PTS)   // 1024 t-values per block
#define K1P  5              // half2 pairs for layer-1 reduction (K=10)
#define K2P  16             // half2 pairs for layer-2 reduction (K=32)

__device__ inline h2 pack2(float a, float b) {
#if __has_builtin(__builtin_amdgcn_cvt_pkrtz)
    h2a t = __builtin_amdgcn_cvt_pkrtz(a, b);   // v_cvt_pkrtz_f16_f32
    return __builtin_bit_cast(h2, t);
#else
    h2 r; r.x = (_Float16)a; r.y = (_Float16)b; return r;
#endif
}

__device__ inline float dot2(h2 a, h2 b, float c) {
#if __has_builtin(__builtin_amdgcn_fdot2)
    return __builtin_amdgcn_fdot2(a, b, c, false);  // v_dot2_f32_f16: 2 FMAs/inst
#else
    return c + (float)a.x * (float)b.x + (float)a.y * (float)b.y;
#endif
}

// __launch_bounds__(256,2): min 2 waves/EU -> VGPR cap 256. Live set ~140 VGPR
// (wh 20 + h1h 64 + wj 16 + temps); at 100-VGPR default the compiler spilled
// h1 to AGPRs (v_accvgpr traffic doubled the inner loop -> 172us @ 100% VALU).
__global__ __launch_bounds__(BDIM, 2)
void hurst_mlp_kernel(const float* __restrict__ returns,
                      const float* __restrict__ W1, const float* __restrict__ b1,
                      const float* __restrict__ W2, const float* __restrict__ b2,
                      const float* __restrict__ W3, const float* __restrict__ b3,
                      float* __restrict__ out, int T)
{
    // Weights transposed + packed to half2 in LDS. Row-contiguous over the
    // reduction index; addresses in the compute loops are wave-uniform ->
    // broadcast reads, no bank conflicts.
    __shared__ h2    sW1h[HID][8];    // [j][k2] = (W1[2k2][j], W1[2k2+1][j]); stride 8 for 16B-aligned rows
    __shared__ h2    sW2h[HID][K2P];  // [j][i2] = (W2[2i2][j], W2[2i2+1][j]); 64B rows -> ds_read_b128 x4
    __shared__ float sb1[HID];
    __shared__ float sb2[HID];
    __shared__ float sW3[HID];
    __shared__ float sb3s;
    __shared__ float sret[TILE + WS];

    const int tid = threadIdx.x;

    // ---- stage + convert weights (fp32 -> half2, transposed) ----
    if (tid < HID * K1P) {            // 160 items
        int j = tid & (HID - 1), k2 = tid >> 5;
        sW1h[j][k2] = pack2(W1[(2 * k2) * HID + j], W1[(2 * k2 + 1) * HID + j]);
    }
    for (int idx = tid; idx < HID * K2P; idx += BDIM) {  // 512 items
        int j = idx & (HID - 1), k2 = idx >> 5;
        sW2h[j][k2] = pack2(W2[(2 * k2) * HID + j], W2[(2 * k2 + 1) * HID + j]);
    }
    if (tid < HID) { sb1[tid] = b1[tid]; sb2[tid] = b2[tid]; sW3[tid] = W3[tid]; }
    if (tid == 0)  { sb3s = b3[0]; }

    const int    b    = blockIdx.y;
    const int    t0   = blockIdx.x * TILE;
    const int    base = (t0 >= WS) ? (t0 - WS) : 0;
    const size_t row  = (size_t)b * (size_t)T;

    for (int i = tid; i < TILE + WS; i += BDIM) {
        int g = base + i;
        sret[i] = (g < T) ? returns[row + g] : 0.0f;
    }
    __syncthreads();

    // ---- load 4 windows/thread, pack to half2 pairs (k,k+1) ----
    h2 wh[PTS][K1P];
    #pragma unroll
    for (int p = 0; p < PTS; ++p) {
        int t   = t0 + p * BDIM + tid;
        int s   = (t >= WS) ? (t - WS) : 0;   // head columns (t<10) reuse window 0
        int off = s - base;
        #pragma unroll
        for (int k2 = 0; k2 < K1P; ++k2)
            wh[p][k2] = pack2(sret[off + 2 * k2], sret[off + 2 * k2 + 1]);
    }

    // ---- layer 1: h1 = relu(window @ W1 + b1), output packed as half2 pairs ----
    h2 h1h[PTS][K2P];   // pair jp holds (h1[2jp], h1[2jp+1]); 16 regs/point
    #pragma unroll
    for (int jp = 0; jp < HID / 2; ++jp) {
        int j0 = 2 * jp, j1 = 2 * jp + 1;
        h2 a0[K1P], a1[K1P];
        #pragma unroll
        for (int k2 = 0; k2 < K1P; ++k2) { a0[k2] = sW1h[j0][k2]; a1[k2] = sW1h[j1][k2]; }
        float bb0 = sb1[j0], bb1 = sb1[j1];
        #pragma unroll
        for (int p = 0; p < PTS; ++p) {
            float x0 = bb0, x1 = bb1;
            #pragma unroll
            for (int k2 = 0; k2 < K1P; ++k2) {
                x0 = dot2(wh[p][k2], a0[k2], x0);
                x1 = dot2(wh[p][k2], a1[k2], x1);
            }
            h1h[p][jp] = pack2(fmaxf(x0, 0.0f), fmaxf(x1, 0.0f));
        }
    }

    // ---- layer 2 + 3 fused: s += W3[j] * relu(h1 @ W2[:,j] + b2[j]) ----
    float sacc[PTS];
    #pragma unroll
    for (int p = 0; p < PTS; ++p) sacc[p] = sb3s;

    #pragma unroll 8
    for (int j = 0; j < HID; ++j) {
        h2 wj[K2P];
        #pragma unroll
        for (int i2 = 0; i2 < K2P; ++i2) wj[i2] = sW2h[j][i2];
        float bj  = sb2[j];
        float w3j = sW3[j];
        #pragma unroll
        for (int p = 0; p < PTS; ++p) {
            float acc = bj;
            #pragma unroll
            for (int i2 = 0; i2 < K2P; ++i2) acc = dot2(h1h[p][i2], wj[i2], acc);
            sacc[p] = fmaf(fmaxf(acc, 0.0f), w3j, sacc[p]);
        }
    }

    // ---- epilogue: 0.5 * sigmoid(s) ----
    #pragma unroll
    for (int p = 0; p < PTS; ++p) {
        int t = t0 + p * BDIM + tid;
        float o = 0.5f / (1.0f + __expf(-sacc[p]));
        out[row + t] = o;
    }
}

extern "C" void kernel_launch(void* const* d_in, const int* in_sizes, int n_in,
                              void* d_out, int out_size, void* d_ws, size_t ws_size,
                              hipStream_t stream) {
    const float* returns = (const float*)d_in[0];
    const float* W1      = (const float*)d_in[1];
    const float* b1      = (const float*)d_in[2];
    const float* W2      = (const float*)d_in[3];
    const float* b2      = (const float*)d_in[4];
    const float* W3      = (const float*)d_in[5];
    const float* b3      = (const float*)d_in[6];
    float* out = (float*)d_out;

    const int T = 4096;
    const int B = out_size / T;   // 1024

    dim3 grid(T / TILE, B, 1);    // (4, 1024)
    dim3 block(BDIM, 1, 1);
    hurst_mlp_kernel<<<grid, block, 0, stream>>>(returns, W1, b1, W2, b2, W3, b3, out, T);
}

// Round 5
// 150.950 us; speedup vs baseline: 1.4224x; 1.1459x over previous
//
#include <hip/hip_runtime.h>
#include <math.h>

typedef _Float16 f16x8 __attribute__((ext_vector_type(8)));   // MFMA A/B operand (4 VGPRs)
typedef float    f32x4 __attribute__((ext_vector_type(4)));   // MFMA C/D operand

#define WS      10
#define HID     32
#define BDIM    256
#define NWAVE   4
#define GM      16                 // points per MFMA group (M)
#define TILE    1024               // t-points per block
#define NGRP    (TILE / GM)        // 64 groups per block
#define H1S     40                 // H1 LDS row stride in f16 units (80B): 16B-aligned, conflict-free b128

__global__ __launch_bounds__(BDIM)
void hurst_mlp_mfma(const float* __restrict__ returns,
                    const float* __restrict__ W1, const float* __restrict__ b1,
                    const float* __restrict__ W2, const float* __restrict__ b2,
                    const float* __restrict__ W3, const float* __restrict__ b3,
                    float* __restrict__ out, int T)
{
    __shared__ float sret[TILE + WS];
    // wave-private transpose buffers (per-wave DS ops are in-order: no barrier needed)
    __shared__ __align__(16) _Float16 h1buf[NWAVE][GM * H1S];

    const int tid  = threadIdx.x;
    const int wid  = tid >> 6;
    const int lane = tid & 63;
    const int col  = lane & 15;    // n (B-col / C-col) or m (A-row)
    const int quad = lane >> 4;    // selects k-octet (A/B) or row-quad (C/D)

    // ---- per-lane B-fragments: B[k = quad*8+jj][n = col + 16*half] ----
    f16x8 bW1[2], bW2[2];
    #pragma unroll
    for (int half = 0; half < 2; ++half) {
        const int n = col + 16 * half;
        #pragma unroll
        for (int jj = 0; jj < 8; ++jj) {
            const int k  = quad * 8 + jj;
            const int kc = (k < WS) ? k : (WS - 1);       // clamped (in-bounds) load
            float v1 = W1[kc * HID + n];
            if (k >= WS) v1 = 0.0f;                        // zero-pad K 10 -> 32
            bW1[half][jj] = (_Float16)v1;
            bW2[half][jj] = (_Float16)W2[k * HID + n];     // K = 32 exact
        }
    }
    const float b1a = b1[col], b1b = b1[col + 16];
    const float b2a = b2[col], b2b = b2[col + 16];
    const float w3a = W3[col], w3b = W3[col + 16];
    const float b3s = b3[0];

    const int    b    = blockIdx.y;
    const int    t0   = blockIdx.x * TILE;
    const int    base = (t0 >= WS) ? (t0 - WS) : 0;
    const size_t row  = (size_t)b * (size_t)T;

    for (int i = tid; i < TILE + WS; i += BDIM) {
        int g = base + i;
        sret[i] = (g < T) ? returns[row + g] : 0.0f;
    }
    __syncthreads();

    _Float16* myH1 = h1buf[wid];

    for (int g = wid; g < NGRP; g += NWAVE) {
        const int tg0 = t0 + g * GM;

        // ---- build X A-fragment: X[m = col][k = quad*8+jj], window start clamped ----
        const int t      = tg0 + col;
        const int wstart = (t >= WS) ? (t - WS) : 0;       // head points reuse window 0
        const int off    = wstart - base;
        f16x8 xf;
        #pragma unroll
        for (int jj = 0; jj < 8; ++jj) {
            const int k  = quad * 8 + jj;
            const int kc = (k < WS) ? k : (WS - 1);
            float v = sret[off + kc];
            if (k >= WS) v = 0.0f;
            xf[jj] = (_Float16)v;
        }

        // ---- layer 1: two 16x16x32 f16 MFMAs -> H1 in C-layout ----
        f32x4 c0 = {0.f, 0.f, 0.f, 0.f}, c1 = {0.f, 0.f, 0.f, 0.f};
        c0 = __builtin_amdgcn_mfma_f32_16x16x32_f16(xf, bW1[0], c0, 0, 0, 0);
        c1 = __builtin_amdgcn_mfma_f32_16x16x32_f16(xf, bW1[1], c1, 0, 0, 0);

        // ---- bias+relu, C-layout -> A-layout transpose through wave-private LDS ----
        #pragma unroll
        for (int r = 0; r < 4; ++r) {
            const int m = quad * 4 + r;                    // C row = point index
            myH1[m * H1S + col]      = (_Float16)fmaxf(c0[r] + b1a, 0.0f);
            myH1[m * H1S + col + 16] = (_Float16)fmaxf(c1[r] + b1b, 0.0f);
        }
        // A2[m = col][k = quad*8+jj]: one 16B-aligned contiguous read
        const f16x8 a2 = *(const f16x8*)&myH1[col * H1S + quad * 8];

        // ---- layer 2: two MFMAs -> H2 in C-layout ----
        f32x4 d0 = {0.f, 0.f, 0.f, 0.f}, d1 = {0.f, 0.f, 0.f, 0.f};
        d0 = __builtin_amdgcn_mfma_f32_16x16x32_f16(a2, bW2[0], d0, 0, 0, 0);
        d1 = __builtin_amdgcn_mfma_f32_16x16x32_f16(a2, bW2[1], d1, 0, 0, 0);

        // ---- layer 3: per-lane W3 combine, quad-wide reduction, sigmoid ----
        float o[4];
        #pragma unroll
        for (int r = 0; r < 4; ++r) {
            float v = w3a * fmaxf(d0[r] + b2a, 0.0f)
                    + w3b * fmaxf(d1[r] + b2b, 0.0f);
            v += __shfl_xor(v, 1);
            v += __shfl_xor(v, 2);
            v += __shfl_xor(v, 4);
            v += __shfl_xor(v, 8);                         // 16-lane quad now uniform
            o[r] = 0.5f / (1.0f + __expf(-(v + b3s)));
        }
        if (col == 0) {                                    // 4 lanes store 4 points each
            f32x4 ov = {o[0], o[1], o[2], o[3]};
            *(f32x4*)&out[row + (size_t)(tg0 + quad * 4)] = ov;
        }
    }
}

extern "C" void kernel_launch(void* const* d_in, const int* in_sizes, int n_in,
                              void* d_out, int out_size, void* d_ws, size_t ws_size,
                              hipStream_t stream) {
    const float* returns = (const float*)d_in[0];
    const float* W1      = (const float*)d_in[1];
    const float* b1      = (const float*)d_in[2];
    const float* W2      = (const float*)d_in[3];
    const float* b2      = (const float*)d_in[4];
    const float* W3      = (const float*)d_in[5];
    const float* b3      = (const float*)d_in[6];
    float* out = (float*)d_out;

    const int T = 4096;
    const int B = out_size / T;   // 1024

    dim3 grid(T / TILE, B, 1);    // (4, 1024)
    dim3 block(BDIM, 1, 1);
    hurst_mlp_mfma<<<grid, block, 0, stream>>>(returns, W1, b1, W2, b2, W3, b3, out, T);
}

// Round 6
// 116.122 us; speedup vs baseline: 1.8490x; 1.2999x over previous
//
#include <hip/hip_runtime.h>
#include <math.h>

typedef _Float16 f16x8  __attribute__((ext_vector_type(8)));    // MFMA A/B operand (4 VGPRs)
typedef float    f32x16 __attribute__((ext_vector_type(16)));   // MFMA C/D operand (32x32)
typedef __fp16   h2a    __attribute__((ext_vector_type(2)));    // cvt_pkrtz result
typedef unsigned u32x4  __attribute__((ext_vector_type(4)));

#define WS    10
#define HID   32
#define BDIM  256
#define NWAVE 4
#define GN    32                  // points per group = MFMA N
#define TILE  1024                // t-points per block
#define NGRP  (TILE / GN)         // 32 groups/block, 8 per wave

__device__ inline unsigned pack2u(float a, float b) {
    h2a t = __builtin_amdgcn_cvt_pkrtz(a, b);   // a -> low16, b -> high16
    return __builtin_bit_cast(unsigned, t);
}

__global__ __launch_bounds__(BDIM, 2)
void hurst_mlp_mfma32(const float* __restrict__ returns,
                      const float* __restrict__ W1, const float* __restrict__ b1,
                      const float* __restrict__ W2, const float* __restrict__ b2,
                      const float* __restrict__ W3, const float* __restrict__ b3,
                      float* __restrict__ out, int T)
{
    __shared__ float sret[TILE + WS];
    __shared__ __align__(16) _Float16 Xh[TILE][16];   // im2col, K=16 (10 + 6 zero-pad), 32B rows

    const int tid  = threadIdx.x;
    const int wid  = tid >> 6;
    const int lane = tid & 63;
    const int n    = lane & 31;    // MFMA m (feature row) for A, n (point) for B/C
    const int hi   = lane >> 5;    // k-half for A/B, row-half for C/D
    const int permidx = (lane ^ 32) << 2;   // cross-half bpermute byte index

    // ---- C-layout row map: row(r) = (r&3) + 8*(r>>2) + 4*hi  [doc-verified 32x32 C/D] ----
    f32x16 b1v, b2v, w3v;
    #pragma unroll
    for (int r = 0; r < 16; ++r) {
        const int rw = (r & 3) + 8 * (r >> 2) + 4 * hi;
        b1v[r] = b1[rw];
        b2v[r] = b2[rw];
        w3v[r] = W3[rw];
    }
    const float b3s = b3[0];

    // ---- A-frags (A[m = lane&31][k = 8*hi + jj]) ----
    f16x8 a1, a2lo, a2hi;
    #pragma unroll
    for (int jj = 0; jj < 8; ++jj) {
        const int k = 8 * hi + jj;
        a1[jj]   = (k < WS) ? (_Float16)W1[k * HID + n] : (_Float16)0.0f;  // W1^T, K 10->16 pad
        a2lo[jj] = (_Float16)W2[k * HID + n];                              // W2^T, k = 0..15
        a2hi[jj] = (_Float16)W2[(16 + k) * HID + n];                       // W2^T, k = 16..31
    }

    const int    b    = blockIdx.y;
    const int    t0   = blockIdx.x * TILE;
    const int    base = (t0 >= WS) ? (t0 - WS) : 0;
    const size_t row  = (size_t)b * (size_t)T;

    for (int i = tid; i < TILE + WS; i += BDIM) {
        int g = base + i;
        sret[i] = (g < T) ? returns[row + g] : 0.0f;
    }
    __syncthreads();

    // ---- build im2col tile: Xh[m][k] = window elem k of point t0+m (head-clamped) ----
    #pragma unroll
    for (int i = 0; i < TILE / BDIM; ++i) {
        const int m   = tid + i * BDIM;
        const int t   = t0 + m;
        const int off = (t >= WS) ? (t - WS - base) : 0;   // t<WS reuses window 0
        u32x4 lo, hi4;
        lo[0]  = pack2u(sret[off + 0], sret[off + 1]);
        lo[1]  = pack2u(sret[off + 2], sret[off + 3]);
        lo[2]  = pack2u(sret[off + 4], sret[off + 5]);
        lo[3]  = pack2u(sret[off + 6], sret[off + 7]);
        hi4[0] = pack2u(sret[off + 8], sret[off + 9]);
        hi4[1] = 0u; hi4[2] = 0u; hi4[3] = 0u;             // k = 10..15 zero
        *(u32x4*)&Xh[m][0] = lo;
        *(u32x4*)&Xh[m][8] = hi4;
    }
    __syncthreads();

    for (int g = wid; g < NGRP; g += NWAVE) {
        const int m0 = g * GN;

        // ---- L1: D1[j][n] = sum_k W1[k][j] * Xh[n][k]; bias via C-init ----
        const f16x8 xb = *(const f16x8*)&Xh[m0 + n][hi * 8];   // B[k=8*hi+jj][n]
        f32x16 d1 = b1v;
        d1 = __builtin_amdgcn_mfma_f32_32x32x16_f16(a1, xb, d1, 0, 0, 0);

        // ---- relu + pack pairs of consecutive j-rows ----
        unsigned pk[8];
        #pragma unroll
        for (int i = 0; i < 8; ++i)
            pk[i] = pack2u(fmaxf(d1[2 * i], 0.0f), fmaxf(d1[2 * i + 1], 0.0f));
        // pk row-pairs: hi=0: (0,1)(2,3)(8,9)(10,11)(16,17)(18,19)(24,25)(26,27)
        //               hi=1: (4,5)(6,7)(12,13)(14,15)(20,21)(22,23)(28,29)(30,31)

        // ---- C-layout -> B-layout redistribution: expose-select + 4 bpermutes ----
        const unsigned s0 = hi ? pk[0] : pk[2];
        const unsigned s1 = hi ? pk[1] : pk[3];
        const unsigned s2 = hi ? pk[4] : pk[6];
        const unsigned s3 = hi ? pk[5] : pk[7];
        const unsigned q0 = (unsigned)__builtin_amdgcn_ds_bpermute(permidx, (int)s0);
        const unsigned q1 = (unsigned)__builtin_amdgcn_ds_bpermute(permidx, (int)s1);
        const unsigned q2 = (unsigned)__builtin_amdgcn_ds_bpermute(permidx, (int)s2);
        const unsigned q3 = (unsigned)__builtin_amdgcn_ds_bpermute(permidx, (int)s3);
        u32x4 blo_u, bhi_u;   // B[k = 8*hi+jj][n] / B[k = 16+8*hi+jj][n] as row pairs
        blo_u[0] = hi ? q0    : pk[0];
        blo_u[1] = hi ? q1    : pk[1];
        blo_u[2] = hi ? pk[2] : q0;
        blo_u[3] = hi ? pk[3] : q1;
        bhi_u[0] = hi ? q2    : pk[4];
        bhi_u[1] = hi ? q3    : pk[5];
        bhi_u[2] = hi ? pk[6] : q2;
        bhi_u[3] = hi ? pk[7] : q3;
        const f16x8 blo = __builtin_bit_cast(f16x8, blo_u);
        const f16x8 bhi = __builtin_bit_cast(f16x8, bhi_u);

        // ---- L2: D2[j2][n] = sum_j W2[j][j2] * h1[j][n]; bias via C-init ----
        f32x16 d2 = b2v;
        d2 = __builtin_amdgcn_mfma_f32_32x32x16_f16(a2lo, blo, d2, 0, 0, 0);
        d2 = __builtin_amdgcn_mfma_f32_32x32x16_f16(a2hi, bhi, d2, 0, 0, 0);

        // ---- L3: per-lane partial over 16 j2-rows, one cross-half reduce ----
        float acc = 0.0f;
        #pragma unroll
        for (int r = 0; r < 16; ++r)
            acc = fmaf(fmaxf(d2[r], 0.0f), w3v[r], acc);
        const int pai = __builtin_amdgcn_ds_bpermute(permidx, __builtin_bit_cast(int, acc));
        acc += __builtin_bit_cast(float, pai);

        // ---- sigmoid epilogue (fast rcp), 32 coalesced stores from half 0 ----
        const float v = acc + b3s;
        const float o = 0.5f * __builtin_amdgcn_rcpf(1.0f + __expf(-v));
        if (hi == 0)
            out[row + (size_t)(t0 + m0 + n)] = o;
    }
}

extern "C" void kernel_launch(void* const* d_in, const int* in_sizes, int n_in,
                              void* d_out, int out_size, void* d_ws, size_t ws_size,
                              hipStream_t stream) {
    const float* returns = (const float*)d_in[0];
    const float* W1      = (const float*)d_in[1];
    const float* b1      = (const float*)d_in[2];
    const float* W2      = (const float*)d_in[3];
    const float* b2      = (const float*)d_in[4];
    const float* W3      = (const float*)d_in[5];
    const float* b3      = (const float*)d_in[6];
    float* out = (float*)d_out;

    const int T = 4096;
    const int B = out_size / T;   // 1024

    dim3 grid(T / TILE, B, 1);    // (4, 1024)
    dim3 block(BDIM, 1, 1);
    hurst_mlp_mfma32<<<grid, block, 0, stream>>>(returns, W1, b1, W2, b2, W3, b3, out, T);
}

// Round 7
// 113.002 us; speedup vs baseline: 1.9000x; 1.0276x over previous
//
#include <hip/hip_runtime.h>
#include <math.h>

typedef _Float16 f16x8  __attribute__((ext_vector_type(8)));    // MFMA A/B operand (4 VGPRs)
typedef float    f32x16 __attribute__((ext_vector_type(16)));   // MFMA C/D operand (32x32)
typedef float    f32x4  __attribute__((ext_vector_type(4)));
typedef __fp16   h2a    __attribute__((ext_vector_type(2)));    // cvt_pkrtz result
typedef unsigned u32x4  __attribute__((ext_vector_type(4)));

#define WS    10
#define HID   32
#define BDIM  256
#define NWAVE 4
#define GN    32                  // points per group = MFMA N
#define TILE  1024                // t-points per block
#define NGRP  (TILE / GN)         // 32 groups/block, 8 per wave

__device__ inline unsigned pack2u(float a, float b) {
    h2a t = __builtin_amdgcn_cvt_pkrtz(a, b);   // a -> low16, b -> high16
    return __builtin_bit_cast(unsigned, t);
}

__global__ __launch_bounds__(BDIM, 2)
void hurst_mlp_mfma32v2(const float* __restrict__ returns,
                        const float* __restrict__ W1, const float* __restrict__ b1,
                        const float* __restrict__ W2, const float* __restrict__ b2,
                        const float* __restrict__ W3, const float* __restrict__ b3,
                        float* __restrict__ out, int T)
{
    __shared__ float sret[TILE + WS];
    __shared__ __align__(16) _Float16 Xh[TILE][16];   // im2col, K=16 (10 + 6 zero-pad)

    const int tid  = threadIdx.x;
    const int wid  = tid >> 6;
    const int lane = tid & 63;
    const int n    = lane & 31;    // MFMA m (A-row) / n (B/C col)
    const int hi   = lane >> 5;    // k-half (A/B) / row-half (C/D)
    const int permidx = (lane ^ 32) << 2;   // cross-half bpermute byte index

    // ---- bias / W3 in C-layout, via dwordx4: row(r)=(r&3)+8(r>>2)+4hi ----
    f32x16 b1v, b2v, w3v;
    #pragma unroll
    for (int i = 0; i < 4; ++i) {
        const f32x4 v1 = ((const f32x4*)b1)[2 * i + hi];
        const f32x4 v2 = ((const f32x4*)b2)[2 * i + hi];
        const f32x4 v3 = ((const f32x4*)W3)[2 * i + hi];
        #pragma unroll
        for (int o = 0; o < 4; ++o) {
            b1v[4 * i + o] = v1[o];
            b2v[4 * i + o] = v2[o];
            w3v[4 * i + o] = v3[o];
        }
    }
    const float b3s = b3[0];

    // ---- A-frags. W2 rows permuted by phi(k)=swap(bit2,bit3): L1's C-layout
    // then IS L2's B-layout lane-locally (no cross-lane redistribution). ----
    f16x8 a1, a2lo, a2hi;
    #pragma unroll
    for (int jj = 0; jj < 8; ++jj) {
        const int k  = 8 * hi + jj;
        a1[jj] = (k < WS) ? (_Float16)W1[k * HID + n] : (_Float16)0.0f;   // W1^T, K 10->16 pad
        const int kf = (k & 3) | ((k & 4) << 1) | ((k & 8) >> 1);         // swap bits 2<->3
        a2lo[jj] = (_Float16)W2[kf * HID + n];
        a2hi[jj] = (_Float16)W2[(16 + kf) * HID + n];
    }

    const int    b    = blockIdx.y;
    const int    t0   = blockIdx.x * TILE;
    const int    base = (t0 >= WS) ? (t0 - WS) : 0;
    const size_t row  = (size_t)b * (size_t)T;

    for (int i = tid; i < TILE + WS; i += BDIM) {
        int g = base + i;
        sret[i] = (g < T) ? returns[row + g] : 0.0f;
    }
    __syncthreads();

    // ---- im2col tile: Xh[m][k] = window elem k of point t0+m (head-clamped) ----
    #pragma unroll
    for (int i = 0; i < TILE / BDIM; ++i) {
        const int m   = tid + i * BDIM;
        const int t   = t0 + m;
        const int off = (t >= WS) ? (t - WS - base) : 0;   // t<WS reuses window 0
        u32x4 lo, hi4;
        lo[0]  = pack2u(sret[off + 0], sret[off + 1]);
        lo[1]  = pack2u(sret[off + 2], sret[off + 3]);
        lo[2]  = pack2u(sret[off + 4], sret[off + 5]);
        lo[3]  = pack2u(sret[off + 6], sret[off + 7]);
        hi4[0] = pack2u(sret[off + 8], sret[off + 9]);
        hi4[1] = 0u; hi4[2] = 0u; hi4[3] = 0u;             // k = 10..15 zero
        *(u32x4*)&Xh[m][0] = lo;
        *(u32x4*)&Xh[m][8] = hi4;
    }
    __syncthreads();

    // ---- group loop, X-frag prefetched one iteration ahead ----
    f16x8 xb = *(const f16x8*)&Xh[wid * GN + n][hi * 8];
    for (int g = wid; g < NGRP; g += NWAVE) {
        const int gn = (g + NWAVE < NGRP) ? (g + NWAVE) : g;
        const f16x8 xb_next = *(const f16x8*)&Xh[gn * GN + n][hi * 8];

        // L1: D1[j][n] = sum_k W1[k][j]*X[n][k], bias via C-init
        f32x16 d1 = b1v;
        d1 = __builtin_amdgcn_mfma_f32_32x32x16_f16(a1, xb, d1, 0, 0, 0);

        // relu + pack: lane-local pairs ARE the L2 B-operand (phi-permuted W2)
        u32x4 blo_u, bhi_u;
        #pragma unroll
        for (int i = 0; i < 4; ++i) {
            blo_u[i] = pack2u(fmaxf(d1[2 * i],     0.0f), fmaxf(d1[2 * i + 1], 0.0f));
            bhi_u[i] = pack2u(fmaxf(d1[8 + 2 * i], 0.0f), fmaxf(d1[9 + 2 * i], 0.0f));
        }

        // L2: bias via C-init
        f32x16 d2 = b2v;
        d2 = __builtin_amdgcn_mfma_f32_32x32x16_f16(a2lo, __builtin_bit_cast(f16x8, blo_u), d2, 0, 0, 0);
        d2 = __builtin_amdgcn_mfma_f32_32x32x16_f16(a2hi, __builtin_bit_cast(f16x8, bhi_u), d2, 0, 0, 0);

        // L3: per-lane partial over 16 rows + one cross-half reduce
        float acc = 0.0f;
        #pragma unroll
        for (int r = 0; r < 16; ++r)
            acc = fmaf(fmaxf(d2[r], 0.0f), w3v[r], acc);
        acc += __builtin_bit_cast(float,
                 __builtin_amdgcn_ds_bpermute(permidx, __builtin_bit_cast(int, acc)));

        // sigmoid epilogue; 32 coalesced stores from half 0
        const float o = 0.5f * __builtin_amdgcn_rcpf(1.0f + __expf(-(acc + b3s)));
        if (hi == 0)
            out[row + (size_t)(t0 + g * GN + n)] = o;

        xb = xb_next;
    }
}

extern "C" void kernel_launch(void* const* d_in, const int* in_sizes, int n_in,
                              void* d_out, int out_size, void* d_ws, size_t ws_size,
                              hipStream_t stream) {
    const float* returns = (const float*)d_in[0];
    const float* W1      = (const float*)d_in[1];
    const float* b1      = (const float*)d_in[2];
    const float* W2      = (const float*)d_in[3];
    const float* b2      = (const float*)d_in[4];
    const float* W3      = (const float*)d_in[5];
    const float* b3      = (const float*)d_in[6];
    float* out = (float*)d_out;

    const int T = 4096;
    const int B = out_size / T;   // 1024

    dim3 grid(T / TILE, B, 1);    // (4, 1024)
    dim3 block(BDIM, 1, 1);
    hurst_mlp_mfma32v2<<<grid, block, 0, stream>>>(returns, W1, b1, W2, b2, W3, b3, out, T);
}

// Round 8
// 106.359 us; speedup vs baseline: 2.0187x; 1.0625x over previous
//
#include <hip/hip_runtime.h>
#include <math.h>

typedef _Float16 f16x8  __attribute__((ext_vector_type(8)));    // MFMA A/B operand (4 VGPRs)
typedef _Float16 h2v    __attribute__((ext_vector_type(2)));
typedef float    f32x16 __attribute__((ext_vector_type(16)));   // MFMA C/D operand (32x32)
typedef float    f32x4  __attribute__((ext_vector_type(4)));
typedef __fp16   h2a    __attribute__((ext_vector_type(2)));    // cvt_pkrtz result
typedef unsigned u32x4  __attribute__((ext_vector_type(4)));

#define WS    10
#define HID   32
#define BDIM  256
#define NWAVE 4
#define GN    32                  // points per group = MFMA N
#define TILE  1024                // t-points per block
#define NGRP  (TILE / GN)         // 32 groups/block, 8 per wave

__device__ inline unsigned pack2u(float a, float b) {
    h2a t = __builtin_amdgcn_cvt_pkrtz(a, b);   // a -> low16, b -> high16
    return __builtin_bit_cast(unsigned, t);
}
__device__ inline unsigned relu2(unsigned u) {  // v_pk_max_f16 with 0
    h2v x = __builtin_bit_cast(h2v, u);
    h2v z = {(_Float16)0.0f, (_Float16)0.0f};
    return __builtin_bit_cast(unsigned, __builtin_elementwise_max(x, z));
}

// (256,4): force total regs <=128/lane -> 16 waves/CU. Live set ~125:
// d1(16)+d2(16)+b1v/b2v/w3v(48, loop-invariant C-operands) + ~45 arch.
__global__ __launch_bounds__(BDIM, 4)
void hurst_mlp_v3(const float* __restrict__ returns,
                  const float* __restrict__ W1, const float* __restrict__ b1,
                  const float* __restrict__ W2, const float* __restrict__ b2,
                  const float* __restrict__ W3, const float* __restrict__ b3,
                  float* __restrict__ out, int T)
{
    __shared__ __align__(16) _Float16 Xh[TILE][16];   // im2col, exactly 32 KB LDS

    const int tid  = threadIdx.x;
    const int wid  = tid >> 6;
    const int lane = tid & 63;
    const int n    = lane & 31;    // MFMA m (A-row) / n (B/C col)
    const int hi   = lane >> 5;    // k-half (A/B) / row-half (C/D)
    const int permidx = (lane ^ 32) << 2;   // cross-half bpermute byte index

    // ---- bias / W3 in C-layout via dwordx4: row(r)=(r&3)+8(r>>2)+4hi ----
    f32x16 b1v, b2v, w3v;
    #pragma unroll
    for (int i = 0; i < 4; ++i) {
        const f32x4 v1 = ((const f32x4*)b1)[2 * i + hi];
        const f32x4 v2 = ((const f32x4*)b2)[2 * i + hi];
        const f32x4 v3 = ((const f32x4*)W3)[2 * i + hi];
        #pragma unroll
        for (int o = 0; o < 4; ++o) {
            b1v[4 * i + o] = v1[o];
            b2v[4 * i + o] = v2[o];
            w3v[4 * i + o] = v3[o];
        }
    }
    const float b3s = b3[0];

    // ---- A-frags. W2 rows permuted by phi(k)=swap(bit2,bit3): L1's C-layout
    // then IS L2's B-layout lane-locally (verified r6/r7, absmax 1.95e-3). ----
    f16x8 a1, a2lo, a2hi;
    #pragma unroll
    for (int jj = 0; jj < 8; ++jj) {
        const int k  = 8 * hi + jj;
        a1[jj] = (k < WS) ? (_Float16)W1[k * HID + n] : (_Float16)0.0f;   // W1^T, K 10->16 pad
        const int kf = (k & 3) | ((k & 4) << 1) | ((k & 8) >> 1);         // swap bits 2<->3
        a2lo[jj] = (_Float16)W2[kf * HID + n];
        a2hi[jj] = (_Float16)W2[(16 + kf) * HID + n];
    }

    const int    b   = blockIdx.y;
    const int    t0  = blockIdx.x * TILE;
    const size_t row = (size_t)b * (size_t)T;

    // ---- im2col build, straight from global (no sret staging) ----
    if (blockIdx.x != 0) {
        // 4 consecutive points per thread; their 4 windows live in 16
        // consecutive floats: returns[base .. base+15], base = t0+4*tid-12
        // (16B-aligned; base >= 1012, base+15 <= 4095: in-bounds).
        const int base = t0 + 4 * tid - 12;
        f32x4 fl0 = *(const f32x4*)&returns[row + base];
        f32x4 fl1 = *(const f32x4*)&returns[row + base + 4];
        f32x4 fl2 = *(const f32x4*)&returns[row + base + 8];
        f32x4 fl3 = *(const f32x4*)&returns[row + base + 12];
        float fl[16];
        #pragma unroll
        for (int o = 0; o < 4; ++o) {
            fl[o] = fl0[o]; fl[4 + o] = fl1[o]; fl[8 + o] = fl2[o]; fl[12 + o] = fl3[o];
        }
        #pragma unroll
        for (int j = 0; j < 4; ++j) {
            const int m = 4 * tid + j;          // window elems = fl[j+2 .. j+11]
            u32x4 lo, hi4;
            lo[0]  = pack2u(fl[j + 2],  fl[j + 3]);
            lo[1]  = pack2u(fl[j + 4],  fl[j + 5]);
            lo[2]  = pack2u(fl[j + 6],  fl[j + 7]);
            lo[3]  = pack2u(fl[j + 8],  fl[j + 9]);
            hi4[0] = pack2u(fl[j + 10], fl[j + 11]);
            hi4[1] = 0u; hi4[2] = 0u; hi4[3] = 0u;   // k = 10..15 zero-pad
            *(u32x4*)&Xh[m][0] = lo;
            *(u32x4*)&Xh[m][8] = hi4;
        }
    } else {
        // block 0: head-clamped scalar path (t<10 reuses window 0); 1/4096 blocks
        #pragma unroll
        for (int j = 0; j < 4; ++j) {
            const int m  = 4 * tid + j;
            const int ws = (m >= WS) ? (m - WS) : 0;
            float fw[WS];
            #pragma unroll
            for (int k = 0; k < WS; ++k) fw[k] = returns[row + ws + k];
            u32x4 lo, hi4;
            lo[0]  = pack2u(fw[0], fw[1]);
            lo[1]  = pack2u(fw[2], fw[3]);
            lo[2]  = pack2u(fw[4], fw[5]);
            lo[3]  = pack2u(fw[6], fw[7]);
            hi4[0] = pack2u(fw[8], fw[9]);
            hi4[1] = 0u; hi4[2] = 0u; hi4[3] = 0u;
            *(u32x4*)&Xh[m][0] = lo;
            *(u32x4*)&Xh[m][8] = hi4;
        }
    }
    __syncthreads();

    // ---- group loop, X-frag prefetched one iteration ahead ----
    f16x8 xb = *(const f16x8*)&Xh[wid * GN + n][hi * 8];
    for (int g = wid; g < NGRP; g += NWAVE) {
        const int gn = (g + NWAVE < NGRP) ? (g + NWAVE) : g;
        const f16x8 xb_next = *(const f16x8*)&Xh[gn * GN + n][hi * 8];

        // L1: D1[j][n] = sum_k W1[k][j]*X[n][k]; bias rides the C-operand
        f32x16 d1 = __builtin_amdgcn_mfma_f32_32x32x16_f16(a1, xb, b1v, 0, 0, 0);

        // relu+pack: lane-local pairs ARE the L2 B-operand (phi-permuted W2)
        u32x4 blo_u, bhi_u;
        #pragma unroll
        for (int i = 0; i < 4; ++i) {
            blo_u[i] = relu2(pack2u(d1[2 * i],     d1[2 * i + 1]));
            bhi_u[i] = relu2(pack2u(d1[8 + 2 * i], d1[9 + 2 * i]));
        }

        // L2 (serial accumulate keeps regs <=128: no split)
        f32x16 d2 = __builtin_amdgcn_mfma_f32_32x32x16_f16(
                        a2lo, __builtin_bit_cast(f16x8, blo_u), b2v, 0, 0, 0);
        d2 = __builtin_amdgcn_mfma_f32_32x32x16_f16(
                        a2hi, __builtin_bit_cast(f16x8, bhi_u), d2, 0, 0, 0);

        // L3: per-lane partial over 16 rows + one cross-half reduce
        float acc = 0.0f;
        #pragma unroll
        for (int r = 0; r < 16; ++r)
            acc = fmaf(fmaxf(d2[r], 0.0f), w3v[r], acc);
        acc += __builtin_bit_cast(float,
                 __builtin_amdgcn_ds_bpermute(permidx, __builtin_bit_cast(int, acc)));

        // sigmoid epilogue; 32 coalesced stores from half 0
        const float o = 0.5f * __builtin_amdgcn_rcpf(1.0f + __expf(-(acc + b3s)));
        if (hi == 0)
            out[row + (size_t)(t0 + g * GN + n)] = o;

        xb = xb_next;
    }
}

extern "C" void kernel_launch(void* const* d_in, const int* in_sizes, int n_in,
                              void* d_out, int out_size, void* d_ws, size_t ws_size,
                              hipStream_t stream) {
    const float* returns = (const float*)d_in[0];
    const float* W1      = (const float*)d_in[1];
    const float* b1      = (const float*)d_in[2];
    const float* W2      = (const float*)d_in[3];
    const float* b2      = (const float*)d_in[4];
    const float* W3      = (const float*)d_in[5];
    const float* b3      = (const float*)d_in[6];
    float* out = (float*)d_out;

    const int T = 4096;
    const int B = out_size / T;   // 1024

    dim3 grid(T / TILE, B, 1);    // (4, 1024)
    dim3 block(BDIM, 1, 1);
    hurst_mlp_v3<<<grid, block, 0, stream>>>(returns, W1, b1, W2, b2, W3, b3, out, T);
}